// Round 5
// baseline (124.207 us; speedup 1.0000x reference)
//
#include <hip/hip_runtime.h>

#define EPSF 1e-12f
#define STILE 32
#define KK 64
#define QSTR 65                 // quads per spline row (63 used + pad, odd -> rotates 4-bank groups)
#define ROWF (QSTR * 4)         // 260 floats per row in the prep (scratch) view
#define BLK 512
#define ENT ((STILE * KK) / BLK)  // 4 prep entries per thread
#define UNROLL 8

__device__ __forceinline__ float sgnf(float x) {
    return (x > 0.f) ? 1.f : ((x < 0.f) ? -1.f : 0.f);
}

// Fused single kernel. Block owns 32 spline rows:
//  prep: stage y, compute delta + PCHIP slopes in a float-view of the quad
//        plane (y@+0, delta@+64, d@+128 within each 260-float row), then pack
//        power-basis (c0,c1,c2,c3) quads in-place (register-buffered).
//  eval: per element 1x ds_read_b128 + Horner; branch-free extrapolation via
//        res = P(t) + P'(t)*(tf - clamp(tf)).
// 33.3 KB LDS -> 4 blocks/CU (32 waves/CU) for latency hiding.
__global__ __launch_bounds__(BLK, 8) void pchip_fused3(
    const float* __restrict__ xq,
    const float* __restrict__ coeffs,
    const float* __restrict__ knots,
    float* __restrict__ out,
    int S, int b_chunk)
{
    __shared__ float4 quads[STILE * QSTR];   // 33280 B
    __shared__ float skn[KK];
    float* fp = (float*)quads;               // prep scratch view

    int tid = threadIdx.x;
    int s0 = blockIdx.x * STILE;
    int b0 = blockIdx.y * b_chunk;

    if (tid < KK) skn[tid] = knots[tid];
    // ---- stage y (coalesced) ----
#pragma unroll
    for (int i = 0; i < ENT; i++) {
        int p = tid + i * BLK;
        int sl = p >> 6, k = p & 63;
        fp[sl * ROWF + k] = coeffs[(size_t)(s0 + sl) * KK + k];
    }
    __syncthreads();
    // ---- delta ----
#pragma unroll
    for (int i = 0; i < ENT; i++) {
        int p = tid + i * BLK;
        int sl = p >> 6, k = p & 63;
        if (k < KK - 1) {
            float h = skn[k + 1] - skn[k];
            fp[sl * ROWF + 64 + k] =
                (fp[sl * ROWF + k + 1] - fp[sl * ROWF + k]) / (h + EPSF);
        }
    }
    __syncthreads();
    // ---- Fritsch-Carlson slopes ----
    float dreg[ENT];
#pragma unroll
    for (int i = 0; i < ENT; i++) {
        int p = tid + i * BLK;
        int sl = p >> 6, k = p & 63;
        const float* del = fp + sl * ROWF + 64;
        float d;
        if (k == 0) {
            float h0 = skn[1] - skn[0], h1 = skn[2] - skn[1];
            float de0 = del[0], de1 = del[1];
            d = ((2.f * h0 + h1) * de0 - h0 * de1) / (h0 + h1 + EPSF);
            if (sgnf(d) != sgnf(de0)) d = 0.f;
            if ((sgnf(de0) != sgnf(de1)) && (fabsf(d) > 3.f * fabsf(de0))) d = 3.f * de0;
        } else if (k == KK - 1) {
            float hn1 = skn[KK - 1] - skn[KK - 2], hn2 = skn[KK - 2] - skn[KK - 3];
            float dn1 = del[KK - 2], dn2 = del[KK - 3];
            d = ((2.f * hn1 + hn2) * dn1 - hn1 * dn2) / (hn1 + hn2 + EPSF);
            if (sgnf(d) != sgnf(dn1)) d = 0.f;
            if ((sgnf(dn1) != sgnf(dn2)) && (fabsf(d) > 3.f * fabsf(dn1))) d = 3.f * dn1;
        } else {
            float dprev = del[k - 1], dnext = del[k];
            float hp = skn[k] - skn[k - 1], hn = skn[k + 1] - skn[k];
            bool same = dprev * dnext > 0.f;
            float w1 = 2.f * hn + hp;
            float w2 = hn + 2.f * hp;
            float denom = w1 / (dprev + EPSF) + w2 / (dnext + EPSF);
            float dint = (w1 + w2) / (denom + EPSF);
            d = same ? dint : 0.f;
        }
        dreg[i] = d;
    }
    __syncthreads();
#pragma unroll
    for (int i = 0; i < ENT; i++) {
        int p = tid + i * BLK;
        int sl = p >> 6, k = p & 63;
        fp[sl * ROWF + 128 + k] = dreg[i];
    }
    __syncthreads();
    // ---- power-basis pack (register-buffered; quads overwrite y region) ----
    float4 qreg[ENT];
#pragma unroll
    for (int i = 0; i < ENT; i++) {
        int p = tid + i * BLK;
        int sl = p >> 6, k = p & 63;
        int kc = min(k, KK - 2);
        const float* row = fp + sl * ROWF;
        float y0 = row[kc], y1 = row[kc + 1];
        float d0 = row[128 + kc], d1 = row[128 + kc + 1];
        float h = skn[kc + 1] - skn[kc] + EPSF;   // reference's h (+EPS)
        qreg[i] = make_float4(y0,
                              h * d0,
                              3.f * (y1 - y0) - h * (2.f * d0 + d1),
                              2.f * (y0 - y1) + h * (d0 + d1));
    }
    __syncthreads();
#pragma unroll
    for (int i = 0; i < ENT; i++) {
        int p = tid + i * BLK;
        int sl = p >> 6, k = p & 63;
        if (k < KK - 1) quads[sl * QSTR + k] = qreg[i];
    }
    __syncthreads();

    // ---- evaluation sweep ----
    float x0d = skn[0], x1d = skn[KK - 1];
    float invh = (float)(KK - 1) / (x1d - x0d);
    float af = invh, bf = -x0d * invh;            // tf = fma(x, af, bf)
    int wave = tid >> 6, lane = tid & 63;
    int srow = lane & 31;                         // s within tile
    int bpar = lane >> 5;                         // b parity within pair
    const float4* qrow = quads + srow * QSTR;

    int pairs_per_wave = b_chunk >> 4;            // (b_chunk/2) / 8 waves
    size_t off0 = (size_t)(b0 + wave * pairs_per_wave * 2 + bpar) * S + s0 + srow;
    for (int ii = 0; ii < pairs_per_wave; ii += UNROLL) {
        float xv[UNROLL];
#pragma unroll
        for (int j = 0; j < UNROLL; j++) xv[j] = xq[off0 + (size_t)(2 * j) * S];
        float rv[UNROLL];
#pragma unroll
        for (int j = 0; j < UNROLL; j++) {
            float x = xv[j];
            float tf = fmaf(x, af, bf);
            float tcf = fminf(fmaxf(tf, 0.f), (float)(KK - 1));
            int idx = min((int)tcf, KK - 2);
            float t = tcf - (float)idx;
            float4 c = qrow[idx];                  // ds_read_b128
            float P = fmaf(fmaf(fmaf(c.w, t, c.z), t, c.y), t, c.x);
            float w = fmaf(fmaf(t, 2.f, t), c.w, c.z + c.z);  // 3t*c3 + 2c2
            float Pp = fmaf(t, w, c.y);                       // P'(t)
            rv[j] = fmaf(Pp, tf - tcf, P);         // exact in-range & extrap
        }
#pragma unroll
        for (int j = 0; j < UNROLL; j++) out[off0 + (size_t)(2 * j) * S] = rv[j];
        off0 += (size_t)(2 * UNROLL) * S;
    }
}

extern "C" void kernel_launch(void* const* d_in, const int* in_sizes, int n_in,
                              void* d_out, int out_size, void* d_ws, size_t ws_size,
                              hipStream_t stream) {
    const float* xq     = (const float*)d_in[0];
    const float* coeffs = (const float*)d_in[1];
    const float* knots  = (const float*)d_in[2];
    float* out = (float*)d_out;

    int K = in_sizes[2];           // 64
    int S = in_sizes[1] / K;       // 4096
    int N = in_sizes[0];           // B*S
    int B = N / S;                 // 4096

    int n_btiles = 8;              // (4096/32) x 8 = 1024 blocks -> 4/CU
    int b_chunk = B / n_btiles;    // 512 b-rows per block
    dim3 grid(S / STILE, n_btiles);
    pchip_fused3<<<grid, BLK, 0, stream>>>(xq, coeffs, knots, out, S, b_chunk);
}